// Round 1
// 172.146 us; speedup vs baseline: 1.0057x; 1.0057x over previous
//
#include <hip/hip_runtime.h>

// AntModel: counts flow through 3 routing layers.
//   dest_k[s] = argmax_j W_k[s, j]   (first max index, ties broken low)
//   layer: out[b, dest[s]] += counts[b, s]; relu == identity (counts >= 0)
// Composition: out[b, dest3[dest2[dest1[s]]]] += x[b, s].
//
// Kernel 1: per-row argmax of W1/W2/W3 (one wave per row, float4 coalesced,
//           loads batched 8-deep for memory-level parallelism — the previous
//           version had VGPR=12 => one load in flight => latency-bound).
// Kernel 2: compose routing tables.
// Kernel 3: per-batch LDS histogram scatter, 1024 threads (16 waves/CU).

#define N_IN   4096
#define N_MID  4096
#define N_OUT  1024
#define BATCH  256

__device__ __forceinline__ void upd(float v, int idx, float& bv, int& bi) {
    // strictly-greater keeps the FIRST occurrence of the max (jnp.argmax semantics)
    if (v > bv || (v == bv && idx < bi)) { bv = v; bi = idx; }
}

template <int NCOLS>
__device__ __forceinline__ void row_argmax(const float* __restrict__ W, int row,
                                           int* __restrict__ dest) {
    const int lane = threadIdx.x & 63;
    const float4* __restrict__ p =
        reinterpret_cast<const float4*>(W + (size_t)row * NCOLS);
    float bv = -__builtin_huge_valf();
    int bi = 0;
    constexpr int ITERS = NCOLS / 256;              // 16 (4096 cols) or 4 (1024)
    constexpr int BAT   = (ITERS >= 8) ? 8 : ITERS; // loads kept in flight
    #pragma unroll
    for (int t0 = 0; t0 < ITERS; t0 += BAT) {
        float4 v[BAT];
        // Issue all BAT loads back-to-back (independent addresses) so the
        // compiler emits counted vmcnt waits: BAT*16B/lane in flight.
        #pragma unroll
        for (int u = 0; u < BAT; ++u)
            v[u] = p[(size_t)(t0 + u) * 64 + lane];
        #pragma unroll
        for (int u = 0; u < BAT; ++u) {
            int c = (t0 + u) * 256 + lane * 4;
            upd(v[u].x, c + 0, bv, bi);
            upd(v[u].y, c + 1, bv, bi);
            upd(v[u].z, c + 2, bv, bi);
            upd(v[u].w, c + 3, bv, bi);
        }
    }
    // wave-64 butterfly reduce; (value desc, index asc) is a total order so
    // xor-reduce is associative/commutative-safe.
    #pragma unroll
    for (int off = 1; off < 64; off <<= 1) {
        float ov = __shfl_xor(bv, off, 64);
        int   oi = __shfl_xor(bi, off, 64);
        if (ov > bv || (ov == bv && oi < bi)) { bv = ov; bi = oi; }
    }
    if (lane == 0) dest[row] = bi;
}

__global__ __launch_bounds__(256) void argmax_all_kernel(
    const float* __restrict__ W1, const float* __restrict__ W2,
    const float* __restrict__ W3, int* __restrict__ dest1,
    int* __restrict__ dest2, int* __restrict__ dest3) {
    const int wave = (blockIdx.x * blockDim.x + threadIdx.x) >> 6;
    if (wave < N_IN) {
        row_argmax<N_MID>(W1, wave, dest1);
    } else if (wave < N_IN + N_MID) {
        row_argmax<N_MID>(W2, wave - N_IN, dest2);
    } else {
        row_argmax<N_OUT>(W3, wave - (N_IN + N_MID), dest3);
    }
}

__global__ __launch_bounds__(256) void compose_kernel(
    const int* __restrict__ dest1, const int* __restrict__ dest2,
    const int* __restrict__ dest3, int* __restrict__ fdest) {
    const int s = blockIdx.x * blockDim.x + threadIdx.x;
    if (s < N_IN) fdest[s] = dest3[dest2[dest1[s]]];
}

__global__ __launch_bounds__(1024) void scatter_kernel(
    const int* __restrict__ x, const int* __restrict__ fdest,
    float* __restrict__ out) {
    __shared__ int cnt[N_OUT];
    const int b   = blockIdx.x;
    const int tid = threadIdx.x;
    cnt[tid] = 0;   // 1024 threads cover N_OUT exactly
    __syncthreads();
    // 4096 sources / 1024 threads = one int4 of counts + one int4 of dests.
    const int4 v = reinterpret_cast<const int4*>(x + (size_t)b * N_IN)[tid];
    const int4 d = reinterpret_cast<const int4*>(fdest)[tid];
    atomicAdd(&cnt[d.x], v.x);
    atomicAdd(&cnt[d.y], v.y);
    atomicAdd(&cnt[d.z], v.z);
    atomicAdd(&cnt[d.w], v.w);
    __syncthreads();
    out[(size_t)b * N_OUT + tid] = (float)cnt[tid];
}

extern "C" void kernel_launch(void* const* d_in, const int* in_sizes, int n_in,
                              void* d_out, int out_size, void* d_ws, size_t ws_size,
                              hipStream_t stream) {
    const int*   x  = (const int*)d_in[0];
    const float* W1 = (const float*)d_in[1];
    const float* W2 = (const float*)d_in[2];
    const float* W3 = (const float*)d_in[3];
    float* out = (float*)d_out;

    int* ws    = (int*)d_ws;
    int* dest1 = ws;               // [4096]
    int* dest2 = ws + N_IN;        // [4096]
    int* dest3 = ws + 2 * N_IN;    // [4096] rows of W3
    int* fdest = ws + 3 * N_IN;    // [4096]

    // 12288 rows total, 1 wave each, 4 waves per 256-thread block.
    const int total_waves = N_IN + N_MID + N_MID;  // 4096*3
    argmax_all_kernel<<<total_waves / 4, 256, 0, stream>>>(W1, W2, W3,
                                                           dest1, dest2, dest3);
    compose_kernel<<<N_IN / 256, 256, 0, stream>>>(dest1, dest2, dest3, fdest);
    scatter_kernel<<<BATCH, 1024, 0, stream>>>(x, fdest, out);
}